// Round 20
// baseline (336.514 us; speedup 1.0000x reference)
//
#include <hip/hip_runtime.h>
#include <hip/hip_bf16.h>

#define NROWS 16384
#define DIM   1024
#define NT    8                          // K-tiles (1024 / 128 i8)
#define NTILE 64                         // 256-row tiles per dim
#define NBLK  (NTILE * (NTILE + 1) / 2)  // 2080 upper-tri blocks (= 8*260)

typedef int i32x4 __attribute__((ext_vector_type(4)));

// monotone float -> uint key (order-preserving), so atomicMax works on floats
__device__ __forceinline__ unsigned fkey(float f) {
    unsigned u = __float_as_uint(f);
    return (u & 0x80000000u) ? ~u : (u | 0x80000000u);
}
__device__ __forceinline__ float funkey(unsigned k) {
    unsigned u = (k & 0x80000000u) ? (k & 0x7fffffffu) : ~k;
    return __uint_as_float(u);
}

// One block per row: fp32 norm, quantize q = round(127*x/||x||) (i8), store
// packed; per-row 1/||q|| so sim is the EXACT cosine of the integer vectors.
__global__ void normalize_rows(const float* __restrict__ x,
                               signed char* __restrict__ xq,
                               float* __restrict__ sinv,
                               unsigned* __restrict__ rowmax) {
    const int row = blockIdx.x;
    const int t = threadIdx.x;                      // 256 threads, 1 float4 each
    const float4 v = ((const float4*)(x + (size_t)row * DIM))[t];
    float ss = v.x * v.x + v.y * v.y + v.z * v.z + v.w * v.w;
#pragma unroll
    for (int off = 32; off > 0; off >>= 1) ss += __shfl_xor(ss, off);
    __shared__ float wss[4];
    __shared__ int   wqs[4];
    if ((t & 63) == 0) wss[t >> 6] = ss;
    __syncthreads();
    const float tot = wss[0] + wss[1] + wss[2] + wss[3];
    const float scale = 127.0f / fmaxf(sqrtf(tot), 1e-12f);
    int qx = __float2int_rn(v.x * scale);
    int qy = __float2int_rn(v.y * scale);
    int qz = __float2int_rn(v.z * scale);
    int qw = __float2int_rn(v.w * scale);
    qx = max(-127, min(127, qx)); qy = max(-127, min(127, qy));
    qz = max(-127, min(127, qz)); qw = max(-127, min(127, qw));
    const int p = (qx & 0xff) | ((qy & 0xff) << 8) | ((qz & 0xff) << 16) | ((qw & 0xff) << 24);
    ((int*)(xq + (size_t)row * DIM))[t] = p;
    int qs = qx * qx + qy * qy + qz * qz + qw * qw;
#pragma unroll
    for (int off = 32; off > 0; off >>= 1) qs += __shfl_xor(qs, off);
    if ((t & 63) == 0) wqs[t >> 6] = qs;
    __syncthreads();
    if (t == 0) {
        const int qtot = max(wqs[0] + wqs[1] + wqs[2] + wqs[3], 1);
        sinv[row] = 1.0f / sqrtf((float)qtot);
        rowmax[row] = 0u;
    }
}

// ---- simmax: i8 256^2, 8-phase m201 schedule with GLOBAL-quadrant phases.
// Phase = one 128x128 C-quadrant of the 256^2 tile: (0,0),(0,1),(1,1),(1,0).
// All 8 waves work inside the quadrant -> each 16KB LDS region {A0,A1,B0,B1}
// is READ at exactly one phase (A0:phi1, B0:phi1[held to phi4], B1:phi2,
// A1:phi3) -> one-phase-lagged staging into the SAME buffer is race-free
// (guarded by each phase's end barrier). Stage order at tile t: phi1 ->
// t+1's A1 (other buf), phi2/3/4 -> t+2's A0/B0/B1 (own buf, regions freed
// phi1/phi1/phi2). ONE vmcnt(6) per tile at phi4 completes ALL of t+1
// (drained loads >=3 phases old); never drains to 0 except tile NT-2.
// Reads/phase/wave: 12,4,8,0 (each fragment read once, held in regs).

__global__ __launch_bounds__(512, 2)
void simmax_kernel(const signed char* __restrict__ xq,
                   const float* __restrict__ sinv,
                   unsigned* __restrict__ rowmax) {
    // bijective XCD-chunked swizzle (2080 = 8 * 260)
    const int bid = blockIdx.x;
    int rem = (bid & 7) * (NBLK / 8) + (bid >> 3);
    int it = 0;
    while (rem >= NTILE - it) { rem -= NTILE - it; ++it; }
    const int jt = it + rem;
    const bool diag = (jt == it);
    const int rowBase = it * 256;
    const int colBase = jt * 256;

    __shared__ __align__(16) char lds[2][4][16384];  // [buf][A0,A1,B0,B1] 128 KiB

    const int t    = threadIdx.x;                    // 512 = 8 waves
    const int lane = t & 63;
    const int wid  = t >> 6;
    const int wrq  = wid >> 2;     // 0..1 : 64-row slice within a quadrant
    const int wcq  = wid & 3;      // 0..3 : 32-col slice within a quadrant
    const int l15  = lane & 15;
    const int hi   = lane >> 4;

    // staging sources per region h: thread covers chunks c=t (j=0) and c=512+t
    // (j=1 -> +64 rows). row = c>>3, ch = c&7; SOURCE col pre-swizzled
    // (ch ^ (row&7)) so the swizzled ds_read finds it; LDS dest linear (#21).
    const int strow = t >> 3;            // 0..63
    const int stcol = ((t & 7) ^ (strow & 7)) * 16;
    const signed char* srcp[4];
    srcp[0] = xq + (size_t)(rowBase +       strow) * DIM + stcol;   // A0
    srcp[1] = xq + (size_t)(rowBase + 128 + strow) * DIM + stcol;   // A1
    srcp[2] = xq + (size_t)(colBase +       strow) * DIM + stcol;   // B0
    srcp[3] = xq + (size_t)(colBase + 128 + strow) * DIM + stcol;   // B1

#define STAGE(h, buf)                                                          \
    do {                                                                       \
        __builtin_amdgcn_global_load_lds(                                      \
            (const __attribute__((address_space(1))) void*)srcp[h],            \
            (__attribute__((address_space(3))) void*)(&lds[buf][h][0] + t * 16), \
            16, 0, 0);                                                         \
        __builtin_amdgcn_global_load_lds(                                      \
            (const __attribute__((address_space(1))) void*)(srcp[h] + (size_t)64 * DIM), \
            (__attribute__((address_space(3))) void*)(&lds[buf][h][0] + (512 + t) * 16), \
            16, 0, 0);                                                         \
        srcp[h] += 128;                                                        \
    } while (0)

    // prologue: t0{A0,B0,B1,A1} -> buf0; t1{A0,B0,B1} -> buf1; vmcnt(6)
    // completes all of t0, leaves t1's 3 half-regions (6 loads) in flight.
    STAGE(0, 0); STAGE(2, 0); STAGE(3, 0); STAGE(1, 0);
    STAGE(0, 1); STAGE(2, 1); STAGE(3, 1);
    asm volatile("s_waitcnt vmcnt(6)" ::: "memory");
    __builtin_amdgcn_s_barrier();

    i32x4 acc[8][4];
#pragma unroll
    for (int m = 0; m < 8; ++m)
#pragma unroll
        for (int n = 0; n < 4; ++n)
            acc[m][n] = (i32x4){0, 0, 0, 0};

    for (int tk = 0; tk < NT; ++tk) {
        const int p = tk & 1;
        const char* curA0 = &lds[p][0][0];
        const char* curA1 = &lds[p][1][0];
        const char* curB0 = &lds[p][2][0];
        const char* curB1 = &lds[p][3][0];
        const bool pf1 = (tk + 1 < NT);
        const bool pf2 = (tk + 2 < NT);

        i32x4 af[4][2], b0[2][2], b1[2][2];

        // ---- phi1: reads A0(8)+B0(4); stage t+1's A1 (other buf); MFMA (0,0)
#pragma unroll
        for (int m2 = 0; m2 < 4; ++m2)
#pragma unroll
            for (int kk = 0; kk < 2; ++kk) {
                const int r = wrq * 64 + m2 * 16 + l15;
                const int chn = (kk * 4 + hi) ^ (r & 7);
                af[m2][kk] = *(const i32x4*)(curA0 + r * 128 + chn * 16);
            }
#pragma unroll
        for (int n2 = 0; n2 < 2; ++n2)
#pragma unroll
            for (int kk = 0; kk < 2; ++kk) {
                const int r = wcq * 32 + n2 * 16 + l15;
                const int chn = (kk * 4 + hi) ^ (r & 7);
                b0[n2][kk] = *(const i32x4*)(curB0 + r * 128 + chn * 16);
            }
        if (pf1) STAGE(1, p ^ 1);
        __builtin_amdgcn_s_barrier();
        asm volatile("s_waitcnt lgkmcnt(0)" ::: "memory");
        __builtin_amdgcn_s_setprio(1);
#pragma unroll
        for (int m2 = 0; m2 < 4; ++m2)
#pragma unroll
            for (int n2 = 0; n2 < 2; ++n2)
#pragma unroll
                for (int kk = 0; kk < 2; ++kk)
                    acc[m2][n2] = __builtin_amdgcn_mfma_i32_16x16x64_i8(
                        af[m2][kk], b0[n2][kk], acc[m2][n2], 0, 0, 0);
        __builtin_amdgcn_s_setprio(0);
        __builtin_amdgcn_s_barrier();

        // ---- phi2: reads B1(4); stage t+2's A0 (own buf, freed phi1); MFMA (0,1)
#pragma unroll
        for (int n2 = 0; n2 < 2; ++n2)
#pragma unroll
            for (int kk = 0; kk < 2; ++kk) {
                const int r = wcq * 32 + n2 * 16 + l15;
                const int chn = (kk * 4 + hi) ^ (r & 7);
                b1[n2][kk] = *(const i32x4*)(curB1 + r * 128 + chn * 16);
            }
        if (pf2) STAGE(0, p);
        __builtin_amdgcn_s_barrier();
        asm volatile("s_waitcnt lgkmcnt(0)" ::: "memory");
        __builtin_amdgcn_s_setprio(1);
#pragma unroll
        for (int m2 = 0; m2 < 4; ++m2)
#pragma unroll
            for (int n2 = 0; n2 < 2; ++n2)
#pragma unroll
                for (int kk = 0; kk < 2; ++kk)
                    acc[m2][n2 + 2] = __builtin_amdgcn_mfma_i32_16x16x64_i8(
                        af[m2][kk], b1[n2][kk], acc[m2][n2 + 2], 0, 0, 0);
        __builtin_amdgcn_s_setprio(0);
        __builtin_amdgcn_s_barrier();

        // ---- phi3: reads A1(8, af reuse); stage t+2's B0 (freed phi1); MFMA (1,1)
#pragma unroll
        for (int m2 = 0; m2 < 4; ++m2)
#pragma unroll
            for (int kk = 0; kk < 2; ++kk) {
                const int r = wrq * 64 + m2 * 16 + l15;
                const int chn = (kk * 4 + hi) ^ (r & 7);
                af[m2][kk] = *(const i32x4*)(curA1 + r * 128 + chn * 16);
            }
        if (pf2) STAGE(2, p);
        __builtin_amdgcn_s_barrier();
        asm volatile("s_waitcnt lgkmcnt(0)" ::: "memory");
        __builtin_amdgcn_s_setprio(1);
#pragma unroll
        for (int m2 = 0; m2 < 4; ++m2)
#pragma unroll
            for (int n2 = 0; n2 < 2; ++n2)
#pragma unroll
                for (int kk = 0; kk < 2; ++kk)
                    acc[m2 + 4][n2 + 2] = __builtin_amdgcn_mfma_i32_16x16x64_i8(
                        af[m2][kk], b1[n2][kk], acc[m2 + 4][n2 + 2], 0, 0, 0);
        __builtin_amdgcn_s_setprio(0);
        __builtin_amdgcn_s_barrier();

        // ---- phi4: no reads; stage t+2's B1 (freed phi2); vmcnt(6) completes
        // ALL of t+1 (leaves t+2's A0,B0,B1 in flight); MFMA (1,0)
        if (pf2) STAGE(3, p);
        if (pf2)      asm volatile("s_waitcnt vmcnt(6)" ::: "memory");
        else if (pf1) asm volatile("s_waitcnt vmcnt(0)" ::: "memory");
        __builtin_amdgcn_s_barrier();
        __builtin_amdgcn_s_setprio(1);
#pragma unroll
        for (int m2 = 0; m2 < 4; ++m2)
#pragma unroll
            for (int n2 = 0; n2 < 2; ++n2)
#pragma unroll
                for (int kk = 0; kk < 2; ++kk)
                    acc[m2 + 4][n2] = __builtin_amdgcn_mfma_i32_16x16x64_i8(
                        af[m2][kk], b0[n2][kk], acc[m2 + 4][n2], 0, 0, 0);
        __builtin_amdgcn_s_setprio(0);
        __builtin_amdgcn_s_barrier();
    }
#undef STAGE

    // ---- epilogue: scaled tile max (R12-verified mapping) ----
    // acc[qm*4+m2][qn*2+n2]; row = qm*128 + wrq*64 + m2*16 + g*4 + r,
    // col = qn*128 + wcq*32 + n2*16 + cl  (C/D layout m89/m91, dtype-indep)
    const int g  = lane >> 4;
    const int cl = lane & 15;

    float scl_col[4];
#pragma unroll
    for (int an = 0; an < 4; ++an)
        scl_col[an] = sinv[colBase + (an >> 1) * 128 + wcq * 32 + (an & 1) * 16 + cl];
    float srw[2][4][4];
#pragma unroll
    for (int qm = 0; qm < 2; ++qm)
#pragma unroll
        for (int m2 = 0; m2 < 4; ++m2)
#pragma unroll
            for (int r = 0; r < 4; ++r)
                srw[qm][m2][r] = sinv[rowBase + qm * 128 + wrq * 64 + m2 * 16 + g * 4 + r];

    // row-direction: rowmax[i] gets max_j (s_j * d_ij); s_i applied in finalize
#pragma unroll
    for (int qm = 0; qm < 2; ++qm)
#pragma unroll
        for (int m2 = 0; m2 < 4; ++m2)
#pragma unroll
            for (int r = 0; r < 4; ++r) {
                const int am = qm * 4 + m2;
                const int grow = qm * 128 + wrq * 64 + m2 * 16 + g * 4 + r;
                float v = -1e30f;
#pragma unroll
                for (int an = 0; an < 4; ++an) {
                    const int gcol = (an >> 1) * 128 + wcq * 32 + (an & 1) * 16 + cl;
                    float f = (float)acc[am][an][r] * scl_col[an];
                    if (diag && grow == gcol) f = -1e30f;   // exclude self-sim
                    v = fmaxf(v, f);
                }
                v = fmaxf(v, __shfl_xor(v, 1));
                v = fmaxf(v, __shfl_xor(v, 2));
                v = fmaxf(v, __shfl_xor(v, 4));
                v = fmaxf(v, __shfl_xor(v, 8));
                if (cl == 0) atomicMax(rowmax + rowBase + grow, fkey(v));
            }

    // col-direction (transpose): max_i (s_i * d_ij); skip on diagonal tiles
    if (!diag) {
#pragma unroll
        for (int an = 0; an < 4; ++an) {
            float v = -1e30f;
#pragma unroll
            for (int qm = 0; qm < 2; ++qm)
#pragma unroll
                for (int m2 = 0; m2 < 4; ++m2)
#pragma unroll
                    for (int r = 0; r < 4; ++r)
                        v = fmaxf(v, (float)acc[qm * 4 + m2][an][r] * srw[qm][m2][r]);
            v = fmaxf(v, __shfl_xor(v, 16));
            v = fmaxf(v, __shfl_xor(v, 32));
            if (g == 0) {
                const int gcol = colBase + (an >> 1) * 128 + wcq * 32 + (an & 1) * 16 + cl;
                atomicMax(rowmax + gcol, fkey(v));
            }
        }
    }
}

__global__ void finalize_kernel(const unsigned* __restrict__ rowmax,
                                const float* __restrict__ sinv,
                                float* __restrict__ out) {
    const int t = threadIdx.x;
    float s = 0.f;
    for (int r = t; r < NROWS; r += 256) {
        const float m = fminf(sinv[r] * funkey(rowmax[r]), 1.0f);   // cos, clamp
        s += logf(2.0f - 2.0f * m + 1e-8f);
    }
#pragma unroll
    for (int off = 32; off > 0; off >>= 1) s += __shfl_xor(s, off);
    __shared__ float ws[4];
    if ((t & 63) == 0) ws[t >> 6] = s;
    __syncthreads();
    if (t == 0) out[0] = -0.5f * (ws[0] + ws[1] + ws[2] + ws[3]) / (float)NROWS;
}

extern "C" void kernel_launch(void* const* d_in, const int* in_sizes, int n_in,
                              void* d_out, int out_size, void* d_ws, size_t ws_size,
                              hipStream_t stream) {
    const float* x = (const float*)d_in[0];
    signed char* xq = (signed char*)d_ws;                                // 16 MB
    float* sinv = (float*)((char*)d_ws + (size_t)NROWS * DIM);           // 64 KB
    unsigned* rowmax = (unsigned*)((char*)d_ws + (size_t)NROWS * DIM + NROWS * sizeof(float));
    float* out = (float*)d_out;

    normalize_rows<<<NROWS, 256, 0, stream>>>(x, xq, sinv, rowmax);
    simmax_kernel<<<NBLK, 512, 0, stream>>>(xq, sinv, rowmax);
    finalize_kernel<<<1, 256, 0, stream>>>(rowmax, sinv, out);
}

// Round 21
// 247.534 us; speedup vs baseline: 1.3595x; 1.3595x over previous
//
#include <hip/hip_runtime.h>
#include <hip/hip_bf16.h>

#define NROWS 16384
#define DIM   1024
#define NT    8                          // K-tiles (1024 / 128 i8)
#define NTILE 128                        // 128-row tiles per dim
#define NBLK  (NTILE * (NTILE + 1) / 2)  // 8256 upper-tri blocks (= 8*1032)
#define SW    16                         // strip width (16 B-panels = 2MB, L2-fit)

typedef int i32x4 __attribute__((ext_vector_type(4)));

// monotone float -> uint key (order-preserving), so atomicMax works on floats
__device__ __forceinline__ unsigned fkey(float f) {
    unsigned u = __float_as_uint(f);
    return (u & 0x80000000u) ? ~u : (u | 0x80000000u);
}
__device__ __forceinline__ float funkey(unsigned k) {
    unsigned u = (k & 0x80000000u) ? (k & 0x7fffffffu) : ~k;
    return __uint_as_float(u);
}

// One block per row: fp32 norm, quantize q = round(127*x/||x||) (i8), store
// packed; also per-row inverse quantized norm s = 1/||q|| so sim is the EXACT
// cosine of the integer vectors (removes norm quantization error).
__global__ void normalize_rows(const float* __restrict__ x,
                               signed char* __restrict__ xq,
                               float* __restrict__ sinv,
                               unsigned* __restrict__ rowmax) {
    const int row = blockIdx.x;
    const int t = threadIdx.x;                      // 256 threads, 1 float4 each
    const float4 v = ((const float4*)(x + (size_t)row * DIM))[t];
    float ss = v.x * v.x + v.y * v.y + v.z * v.z + v.w * v.w;
#pragma unroll
    for (int off = 32; off > 0; off >>= 1) ss += __shfl_xor(ss, off);
    __shared__ float wss[4];
    __shared__ int   wqs[4];
    if ((t & 63) == 0) wss[t >> 6] = ss;
    __syncthreads();
    const float tot = wss[0] + wss[1] + wss[2] + wss[3];
    const float scale = 127.0f / fmaxf(sqrtf(tot), 1e-12f);
    int qx = __float2int_rn(v.x * scale);
    int qy = __float2int_rn(v.y * scale);
    int qz = __float2int_rn(v.z * scale);
    int qw = __float2int_rn(v.w * scale);
    qx = max(-127, min(127, qx)); qy = max(-127, min(127, qy));
    qz = max(-127, min(127, qz)); qw = max(-127, min(127, qw));
    const int p = (qx & 0xff) | ((qy & 0xff) << 8) | ((qz & 0xff) << 16) | ((qw & 0xff) << 24);
    ((int*)(xq + (size_t)row * DIM))[t] = p;
    int qs = qx * qx + qy * qy + qz * qz + qw * qw;
#pragma unroll
    for (int off = 32; off > 0; off >>= 1) qs += __shfl_xor(qs, off);
    if ((t & 63) == 0) wqs[t >> 6] = qs;
    __syncthreads();
    if (t == 0) {
        const int qtot = max(wqs[0] + wqs[1] + wqs[2] + wqs[3], 1);
        sinv[row] = 1.0f / sqrtf((float)qtot);
        rowmax[row] = 0u;
    }
}

// ---- simmax: i8, m97 128^2 single-buffer structure, STRIP-ORDERED traversal.
// Tile order: strips of SW=16 jt-columns; within a strip, it outer / jt inner.
// The strip's 16 B-panels (2 MB) stay L2-resident; each A-panel is read once
// per strip and reused for up to 16 consecutive tiles; rowmax/colmax atomics
// hit a small hot window. XCD chunking (8 x 1032) on top of the strip order.
// [Session best: R14 = 245us total. Schedule variants (phase-pipelines x5,
// B-direct-global x2, fragment-major staging, address hoisting, dbuf,
// LDS-merged atomics) all measured neutral-to-worse -- this is the locked-in
// configuration.]

__global__ __launch_bounds__(256, 4)
void simmax_kernel(const signed char* __restrict__ xq,
                   const float* __restrict__ sinv,
                   unsigned* __restrict__ rowmax) {
    // bijective XCD-chunked swizzle (8256 = 8 * 1032)
    const int bid = blockIdx.x;
    int rem = (bid & 7) * (NBLK / 8) + (bid >> 3);
    // strip-order decode: strip s has 256*s + 136 tiles
    int s = 0;
    for (;;) {
        const int sz = 256 * s + 136;
        if (rem < sz) break;
        rem -= sz;
        ++s;
    }
    int it, jt;
    const int full = 256 * s;            // tiles with it < 16s (full width 16)
    if (rem < full) {
        it = rem >> 4;
        jt = SW * s + (rem & 15);
    } else {
        int r2 = rem - full;
        int d = 0;
        while (r2 >= SW - d) { r2 -= SW - d; ++d; }
        it = SW * s + d;
        jt = it + r2;
    }
    const bool diag = (jt == it);
    const int rowBase = it * 128;
    const int colBase = jt * 128;

    __shared__ __align__(16) char lds[2][128][128];  // [A/B][row][128 B] = 32 KiB

    const int t    = threadIdx.x;                    // 256 = 4 waves
    const int lane = t & 63;
    const int wid  = t >> 6;
    const int wr2  = wid >> 1;     // 0..1 (M)
    const int wc2  = wid & 1;      // 0..1 (N)
    const int l15  = lane & 15;
    const int hi   = lane >> 4;

    // staging: chunk c = j*256 + t (j=0..7); op = c>>10 (A/B); cc = c&1023;
    // row = cc>>3, ch = cc&7. LDS dest LINEAR (c*16 B); SOURCE chunk
    // pre-swizzled (ch ^ (row&7)) so the swizzled ds_read finds it (rule #21).
    const signed char* srcp[8];
#pragma unroll
    for (int j = 0; j < 8; ++j) {
        const int c   = j * 256 + t;
        const int op  = c >> 10;
        const int cc  = c & 1023;
        const int row = cc >> 3;
        const int ch  = cc & 7;
        const int gr  = (op ? colBase : rowBase) + row;
        srcp[j] = xq + (size_t)gr * DIM + (ch ^ (row & 7)) * 16;
    }

    i32x4 acc[4][4];
#pragma unroll
    for (int m = 0; m < 4; ++m)
#pragma unroll
        for (int n = 0; n < 4; ++n)
            acc[m][n] = (i32x4){0, 0, 0, 0};

    char* ldsb = &lds[0][0][0];

    for (int kt = 0; kt < NT; ++kt) {
        __syncthreads();               // previous tile's compute done
#pragma unroll
        for (int j = 0; j < 8; ++j) {
            __builtin_amdgcn_global_load_lds(
                (const __attribute__((address_space(1))) void*)srcp[j],
                (__attribute__((address_space(3))) void*)(ldsb + (j * 256 + wid * 64) * 16),
                16, 0, 0);
            srcp[j] += 128;            // next 128-elem i8 K-tile
        }
        __syncthreads();               // drains vmcnt(0): staged data visible

        i32x4 af[4][2], bf[4][2];
#pragma unroll
        for (int m = 0; m < 4; ++m)
#pragma unroll
            for (int kk = 0; kk < 2; ++kk) {
                const int row = wr2 * 64 + m * 16 + l15;
                const int chn = (kk * 4 + hi) ^ (row & 7);
                af[m][kk] = *(const i32x4*)(&lds[0][0][0] + row * 128 + chn * 16);
            }
#pragma unroll
        for (int n = 0; n < 4; ++n)
#pragma unroll
            for (int kk = 0; kk < 2; ++kk) {
                const int row = wc2 * 64 + n * 16 + l15;
                const int chn = (kk * 4 + hi) ^ (row & 7);
                bf[n][kk] = *(const i32x4*)(&lds[1][0][0] + row * 128 + chn * 16);
            }
#pragma unroll
        for (int m = 0; m < 4; ++m)
#pragma unroll
            for (int n = 0; n < 4; ++n)
#pragma unroll
                for (int kk = 0; kk < 2; ++kk)
                    acc[m][n] = __builtin_amdgcn_mfma_i32_16x16x64_i8(
                        af[m][kk], bf[n][kk], acc[m][n], 0, 0, 0);
    }

    // ---- epilogue: scaled tile max reduction ----
    // C/D layout: col = lane&15, row = (lane>>4)*4 + reg  [m89/m91, dtype-indep]
    const int g  = lane >> 4;
    const int cl = lane & 15;

    // column scales (lane's 4 cols) and row scales (lane's 16 rows)
    float scl_col[4];
#pragma unroll
    for (int n = 0; n < 4; ++n)
        scl_col[n] = sinv[colBase + wc2 * 64 + n * 16 + cl];
    float srow[4][4];
#pragma unroll
    for (int m = 0; m < 4; ++m)
#pragma unroll
        for (int r = 0; r < 4; ++r)
            srow[m][r] = sinv[rowBase + wr2 * 64 + m * 16 + g * 4 + r];

    // row-direction: rowmax[i] takes max_j (s_j * d_ij); s_i applied in finalize
#pragma unroll
    for (int m = 0; m < 4; ++m)
#pragma unroll
        for (int r = 0; r < 4; ++r) {
            const int grow = wr2 * 64 + m * 16 + g * 4 + r;
            float v = -1e30f;
#pragma unroll
            for (int n = 0; n < 4; ++n) {
                const int gcol = wc2 * 64 + n * 16 + cl;
                float f = (float)acc[m][n][r] * scl_col[n];
                if (diag && grow == gcol) f = -1e30f;   // exclude self-sim
                v = fmaxf(v, f);
            }
            v = fmaxf(v, __shfl_xor(v, 1));
            v = fmaxf(v, __shfl_xor(v, 2));
            v = fmaxf(v, __shfl_xor(v, 4));
            v = fmaxf(v, __shfl_xor(v, 8));
            if (cl == 0) atomicMax(rowmax + rowBase + grow, fkey(v));
        }

    // col-direction (transpose contribution): max_i (s_i * d_ij); skip on diag
    if (!diag) {
#pragma unroll
        for (int n = 0; n < 4; ++n) {
            float v = -1e30f;
#pragma unroll
            for (int m = 0; m < 4; ++m)
#pragma unroll
                for (int r = 0; r < 4; ++r)
                    v = fmaxf(v, (float)acc[m][n][r] * srow[m][r]);
            v = fmaxf(v, __shfl_xor(v, 16));
            v = fmaxf(v, __shfl_xor(v, 32));
            if (g == 0) {
                const int gcol = colBase + wc2 * 64 + n * 16 + cl;
                atomicMax(rowmax + gcol, fkey(v));
            }
        }
    }
}

__global__ void finalize_kernel(const unsigned* __restrict__ rowmax,
                                const float* __restrict__ sinv,
                                float* __restrict__ out) {
    const int t = threadIdx.x;
    float s = 0.f;
    for (int r = t; r < NROWS; r += 256) {
        const float m = fminf(sinv[r] * funkey(rowmax[r]), 1.0f);   // cos, clamp
        s += logf(2.0f - 2.0f * m + 1e-8f);
    }
#pragma unroll
    for (int off = 32; off > 0; off >>= 1) s += __shfl_xor(s, off);
    __shared__ float ws[4];
    if ((t & 63) == 0) ws[t >> 6] = s;
    __syncthreads();
    if (t == 0) out[0] = -0.5f * (ws[0] + ws[1] + ws[2] + ws[3]) / (float)NROWS;
}

extern "C" void kernel_launch(void* const* d_in, const int* in_sizes, int n_in,
                              void* d_out, int out_size, void* d_ws, size_t ws_size,
                              hipStream_t stream) {
    const float* x = (const float*)d_in[0];
    signed char* xq = (signed char*)d_ws;                                // 16 MB
    float* sinv = (float*)((char*)d_ws + (size_t)NROWS * DIM);           // 64 KB
    unsigned* rowmax = (unsigned*)((char*)d_ws + (size_t)NROWS * DIM + NROWS * sizeof(float));
    float* out = (float*)d_out;

    normalize_rows<<<NROWS, 256, 0, stream>>>(x, xq, sinv, rowmax);
    simmax_kernel<<<NBLK, 256, 0, stream>>>(xq, sinv, rowmax);
    finalize_kernel<<<1, 256, 0, stream>>>(rowmax, sinv, out);
}